// Round 2
// baseline (74.720 us; speedup 1.0000x reference)
//
#include <hip/hip_runtime.h>
#include <math.h>

// Problem: x,y,z each (4, 256, 32, 32, 32) fp32.
// Per (b,c): S = sum over 2x2x2 windows of max(window) + total_sum/8.
// pooled[b,c] = (Sx+Sy)^2 + (Sy+Sz)^2 + (Sx+Sz)^2
// out[b,:] = pooled[b,:] / max(||pooled[b,:]||_2, 1e-12)

#define BC_TOTAL 1024          // 4 * 256
#define SLICE_ELEMS 32768      // 32*32*32

__global__ __launch_bounds__(256) void pool_sum_kernel(
    const float* __restrict__ x,
    const float* __restrict__ y,
    const float* __restrict__ z,
    float* __restrict__ ws)
{
    const int bc = blockIdx.x;      // 0..1023  -> (b,c) slice
    const int which = blockIdx.y;   // 0..2     -> input select
    const float* __restrict__ p =
        (which == 0 ? x : (which == 1 ? y : z)) + (size_t)bc * SLICE_ELEMS;

    const int t = threadIdx.x;
    // Per-thread invariants: d4 = t&7, ww = (t>>3)&15, wh0 = t>>7.
    // Work item `it` (0..7) has wh = wh0 + 2*it  ->  base walks +4096 floats.
    const float* __restrict__ q =
        p + ((t >> 7) * 2048 + ((t >> 3) & 15) * 64 + (t & 7) * 4);

    float acc0 = 0.0f, acc1 = 0.0f;

    // Two groups of 4 work-items; each group issues 16 float4 loads (64 VGPRs
    // of data) before any consumption -> deep MLP, then consumes.
#pragma unroll
    for (int g = 0; g < 2; ++g) {
        float4 v[16];
#pragma unroll
        for (int j = 0; j < 4; ++j) {
            const float* __restrict__ r = q + (g * 4 + j) * 4096;
            v[4 * j + 0] = *reinterpret_cast<const float4*>(r);          // (h0,w0)
            v[4 * j + 1] = *reinterpret_cast<const float4*>(r + 32);     // (h0,w1)
            v[4 * j + 2] = *reinterpret_cast<const float4*>(r + 1024);   // (h1,w0)
            v[4 * j + 3] = *reinterpret_cast<const float4*>(r + 1056);   // (h1,w1)
        }
#pragma unroll
        for (int j = 0; j < 4; ++j) {
            const float4 a0 = v[4 * j + 0];
            const float4 a1 = v[4 * j + 1];
            const float4 a2 = v[4 * j + 2];
            const float4 a3 = v[4 * j + 3];

            const float mx = fmaxf(fmaxf(a0.x, a1.x), fmaxf(a2.x, a3.x));
            const float my = fmaxf(fmaxf(a0.y, a1.y), fmaxf(a2.y, a3.y));
            const float mz = fmaxf(fmaxf(a0.z, a1.z), fmaxf(a2.z, a3.z));
            const float mw = fmaxf(fmaxf(a0.w, a1.w), fmaxf(a2.w, a3.w));

            const float s = ((a0.x + a0.y) + (a0.z + a0.w))
                          + ((a1.x + a1.y) + (a1.z + a1.w))
                          + ((a2.x + a2.y) + (a2.z + a2.w))
                          + ((a3.x + a3.y) + (a3.z + a3.w));

            const float contrib = fmaxf(mx, my) + fmaxf(mz, mw) + s * 0.125f;
            if (j & 1) acc1 += contrib; else acc0 += contrib;
        }
    }

    float acc = acc0 + acc1;

    // Block reduction: wave shuffle then LDS across 4 waves.
#pragma unroll
    for (int off = 32; off > 0; off >>= 1) acc += __shfl_down(acc, off);

    __shared__ float red[4];
    const int wave = t >> 6;
    if ((t & 63) == 0) red[wave] = acc;
    __syncthreads();
    if (t == 0) {
        ws[which * BC_TOTAL + bc] = (red[0] + red[1]) + (red[2] + red[3]);
    }
}

__global__ __launch_bounds__(256) void finalize_kernel(
    const float* __restrict__ ws, float* __restrict__ out)
{
    const int b = blockIdx.x;   // 0..3
    const int c = threadIdx.x;  // 0..255
    const int bc = b * 256 + c;

    const float Sx = ws[bc];
    const float Sy = ws[BC_TOTAL + bc];
    const float Sz = ws[2 * BC_TOTAL + bc];

    const float xy = Sx + Sy;
    const float yz = Sy + Sz;
    const float xz = Sx + Sz;
    const float pooled = xy * xy + yz * yz + xz * xz;

    float sq = pooled * pooled;
#pragma unroll
    for (int off = 32; off > 0; off >>= 1) sq += __shfl_down(sq, off);

    __shared__ float red[4];
    if ((c & 63) == 0) red[c >> 6] = sq;
    __syncthreads();

    __shared__ float norm_s;
    if (c == 0) norm_s = sqrtf((red[0] + red[1]) + (red[2] + red[3]));
    __syncthreads();

    const float norm = fmaxf(norm_s, 1e-12f);
    out[bc] = pooled / norm;
}

extern "C" void kernel_launch(void* const* d_in, const int* in_sizes, int n_in,
                              void* d_out, int out_size, void* d_ws, size_t ws_size,
                              hipStream_t stream) {
    const float* x = (const float*)d_in[0];
    const float* y = (const float*)d_in[1];
    const float* z = (const float*)d_in[2];
    float* ws = (float*)d_ws;      // 3 * 1024 floats of partial sums
    float* out = (float*)d_out;    // 1024 floats (4 x 256)

    dim3 grid(BC_TOTAL, 3, 1);
    pool_sum_kernel<<<grid, 256, 0, stream>>>(x, y, z, ws);
    finalize_kernel<<<4, 256, 0, stream>>>(ws, out);
}

// Round 3
// 74.143 us; speedup vs baseline: 1.0078x; 1.0078x over previous
//
#include <hip/hip_runtime.h>
#include <math.h>

// Problem: x,y,z each (4, 256, 32, 32, 32) fp32.
// Per (b,c): S = sum over 2x2x2 windows of max(window) + total_sum/8.
// pooled[b,c] = (Sx+Sy)^2 + (Sy+Sz)^2 + (Sx+Sz)^2
// out[b,:] = pooled[b,:] / max(||pooled[b,:]||_2, 1e-12)
//
// Grid: 1024 blocks (one per bc slice) x 512 threads; each block reads all
// three inputs' slices. 1024 = 4*256 -> even block/CU schedule at any
// residency (4/2/1 blocks per CU), no partial-round tail.

#define BC_TOTAL 1024          // 4 * 256
#define SLICE_ELEMS 32768      // 32*32*32

__global__ __launch_bounds__(512) void pool_sum_kernel(
    const float* __restrict__ x,
    const float* __restrict__ y,
    const float* __restrict__ z,
    float* __restrict__ ws)
{
    const int bc = blockIdx.x;      // 0..1023  -> (b,c) slice
    const int t = threadIdx.x;      // 0..511

    // Work item idx = t + 512*it (it=0..3): d4 = idx&7, ww = (idx>>3)&15,
    // wh = idx>>7 = (t>>7) + 4*it. d4/ww invariant per thread; base walks
    // +8192 floats per it.
    const int off0 = (t >> 7) * 2048 + ((t >> 3) & 15) * 64 + (t & 7) * 4;

    float acc[3];

#pragma unroll
    for (int w = 0; w < 3; ++w) {
        const float* __restrict__ q =
            (w == 0 ? x : (w == 1 ? y : z)) + (size_t)bc * SLICE_ELEMS + off0;

        // Batch all 16 loads (4 work-items x 4 corners) before consuming.
        float4 v[16];
#pragma unroll
        for (int it = 0; it < 4; ++it) {
            const float* __restrict__ r = q + it * 8192;
            v[4 * it + 0] = *reinterpret_cast<const float4*>(r);          // (h0,w0)
            v[4 * it + 1] = *reinterpret_cast<const float4*>(r + 32);     // (h0,w1)
            v[4 * it + 2] = *reinterpret_cast<const float4*>(r + 1024);   // (h1,w0)
            v[4 * it + 3] = *reinterpret_cast<const float4*>(r + 1056);   // (h1,w1)
        }
        // Forbid the scheduler from sinking loads into the consume loop:
        // all 16 loads must be issued before any compute below.
        __builtin_amdgcn_sched_barrier(0);

        float a0s = 0.0f, a1s = 0.0f;
#pragma unroll
        for (int it = 0; it < 4; ++it) {
            const float4 a0 = v[4 * it + 0];
            const float4 a1 = v[4 * it + 1];
            const float4 a2 = v[4 * it + 2];
            const float4 a3 = v[4 * it + 3];

            const float mx = fmaxf(fmaxf(a0.x, a1.x), fmaxf(a2.x, a3.x));
            const float my = fmaxf(fmaxf(a0.y, a1.y), fmaxf(a2.y, a3.y));
            const float mz = fmaxf(fmaxf(a0.z, a1.z), fmaxf(a2.z, a3.z));
            const float mw = fmaxf(fmaxf(a0.w, a1.w), fmaxf(a2.w, a3.w));

            const float s = ((a0.x + a0.y) + (a0.z + a0.w))
                          + ((a1.x + a1.y) + (a1.z + a1.w))
                          + ((a2.x + a2.y) + (a2.z + a2.w))
                          + ((a3.x + a3.y) + (a3.z + a3.w));

            const float contrib = fmaxf(mx, my) + fmaxf(mz, mw) + s * 0.125f;
            if (it & 1) a1s += contrib; else a0s += contrib;
        }
        acc[w] = a0s + a1s;
    }

    // Block reduction: wave shuffle (3 values together), then LDS across 8 waves.
#pragma unroll
    for (int off = 32; off > 0; off >>= 1) {
        acc[0] += __shfl_down(acc[0], off);
        acc[1] += __shfl_down(acc[1], off);
        acc[2] += __shfl_down(acc[2], off);
    }

    __shared__ float red[8][3];
    const int wave = t >> 6;
    if ((t & 63) == 0) {
        red[wave][0] = acc[0];
        red[wave][1] = acc[1];
        red[wave][2] = acc[2];
    }
    __syncthreads();
    if (t < 3) {
        float s = 0.0f;
#pragma unroll
        for (int wv = 0; wv < 8; ++wv) s += red[wv][t];
        ws[t * BC_TOTAL + bc] = s;
    }
}

__global__ __launch_bounds__(256) void finalize_kernel(
    const float* __restrict__ ws, float* __restrict__ out)
{
    const int b = blockIdx.x;   // 0..3
    const int c = threadIdx.x;  // 0..255
    const int bc = b * 256 + c;

    const float Sx = ws[bc];
    const float Sy = ws[BC_TOTAL + bc];
    const float Sz = ws[2 * BC_TOTAL + bc];

    const float xy = Sx + Sy;
    const float yz = Sy + Sz;
    const float xz = Sx + Sz;
    const float pooled = xy * xy + yz * yz + xz * xz;

    float sq = pooled * pooled;
#pragma unroll
    for (int off = 32; off > 0; off >>= 1) sq += __shfl_down(sq, off);

    __shared__ float red[4];
    if ((c & 63) == 0) red[c >> 6] = sq;
    __syncthreads();

    __shared__ float norm_s;
    if (c == 0) norm_s = sqrtf((red[0] + red[1]) + (red[2] + red[3]));
    __syncthreads();

    const float norm = fmaxf(norm_s, 1e-12f);
    out[bc] = pooled / norm;
}

extern "C" void kernel_launch(void* const* d_in, const int* in_sizes, int n_in,
                              void* d_out, int out_size, void* d_ws, size_t ws_size,
                              hipStream_t stream) {
    const float* x = (const float*)d_in[0];
    const float* y = (const float*)d_in[1];
    const float* z = (const float*)d_in[2];
    float* ws = (float*)d_ws;      // 3 * 1024 floats of partial sums
    float* out = (float*)d_out;    // 1024 floats (4 x 256)

    pool_sum_kernel<<<BC_TOTAL, 512, 0, stream>>>(x, y, z, ws);
    finalize_kernel<<<4, 256, 0, stream>>>(ws, out);
}